// Round 10
// baseline (353.419 us; speedup 1.0000x reference)
//
#include <hip/hip_runtime.h>
#include <cstdint>

typedef unsigned short u16;
typedef __attribute__((ext_vector_type(4))) int i32x4;

#define DEVI __device__ __forceinline__

// ---- float32 replication of reference ops (np ref computes in f32) ---------
DEVI float pactf(float x, float a) {             // literal op order, f32 CR
    float ax = fabsf(x);
    float w  = fabsf(ax - a);
    float t  = (ax - w) + a;
    float s  = (x > 0.f) ? 0.5f : ((x < 0.f) ? -0.5f : 0.0f);
    return s * t;
}
DEVI float quantf(float x, float r) {            // quant_raw value path, f32
    float xs = x / r;
    xs = fminf(fmaxf(xs, -0.9921875f), 0.9921875f);
    float e = rintf(xs * 128.0f);                // round half-even, exact
    return (e * 0.0078125f) * r;                 // e/128 exact pow2
}
// f32 transcendentals via correctly-rounded f64 -> f32 (bit-matches np/glibc)
DEVI float sigf(float x) {
    float eg  = (float)exp(-(double)x);
    float den = 1.0f + eg;
    return 1.0f / den;
}
DEVI float tanf32(float x) { return (float)tanh((double)x); }

// Table geometry: index k = g*256 (exact for on-grid gates).
#define KSIG  4436
#define NSIG  8873
#define KTANH 2309
#define NTANH 4619

DEVI float sig_lut(float g, const float* __restrict__ Ts) {
    float g256 = g * 256.0f;                     // exact for grid multiples
    float kf = rintf(g256);
    if (kf == g256) {
        if (kf >  (float)KSIG) return 1.0f;
        if (kf < -(float)KSIG) return 0.0f;
        return Ts[(int)kf + KSIG];
    }
    return sigf(g);
}
DEVI float tanh_lut(float g, const float* __restrict__ Tt) {
    float g256 = g * 256.0f;
    float kf = rintf(g256);
    if (kf == g256) {
        if (fabsf(kf) <= (float)KTANH) return Tt[(int)kf + KTANH];
        return copysignf(1.0f, g);
    }
    return tanf32(g);
}

// ---- prep: tables + bias (REORDERED cols n' = h*4+g), fused ----------------
__global__ void prep_misc(const float* __restrict__ b0, const float* __restrict__ b1,
                          float* __restrict__ Bf, float* __restrict__ Ts,
                          float* __restrict__ Tt) {
    int i = blockIdx.x * 256 + threadIdx.x;
    if (i < NSIG)  Ts[i] = sigf((float)(i - KSIG)  * 0.00390625f);
    if (i < NTANH) Tt[i] = tanf32((float)(i - KTANH) * 0.00390625f);
    if (i < 8192) {
        int proj = i >> 12, nn = i & 4095;
        const float* b = proj ? b1 : b0;
        float v = b[nn];
        float xs = fminf(fmaxf(v, -0.9921875f), 0.9921875f);
        int np_ = ((nn & 1023) << 2) | (nn >> 10);   // h*4 + g
        Bf[proj * 4096 + np_] = rintf(xs * 128.f);
    }
}

// ---- prep: bitsplit activations (input + hx fused) -> int8 planes ----------
__global__ void prep_act2(const float* __restrict__ X0, const float* __restrict__ X1,
                          const float* __restrict__ a1p, const float* __restrict__ a11p,
                          signed char* __restrict__ A) {
    int blk = blockIdx.x;
    int lo = (blk < 4096) ? 1 : 0;
    const float* X = lo ? X0 : X1;
    float a = lo ? a1p[0] : a11p[0];
    int planebase = lo ? 0 : 4;
    int idx4 = ((blk & 4095) * 256 + threadIdx.x) * 4;
    float4 xv4 = *(const float4*)(X + idx4);
    float v[4] = {xv4.x, xv4.y, xv4.z, xv4.w};
    signed char e4[4][4];                        // [n][elem]
#pragma unroll
    for (int el = 0; el < 4; el++) {
        float x = pactf(v[el], a) / a;           // f32 division, CR
        float xv = x;
        float beta = 1.0f;
#pragma unroll
        for (int n = 0; n < 4; n++) {
            float xs = xv / beta;                // pow2: exact
            xs = fminf(fmaxf(xs, -0.9921875f), 0.9921875f);
            float e = rintf(xs * 128.0f);        // integer in [-127,127]
            e4[n][el] = (signed char)(int)e;
            float y = e * 0.0078125f;            // e/128 exact
            xv = xv - y * beta;                  // f32 CR (product exact)
            beta = beta * 0.5f;
        }
    }
#pragma unroll
    for (int n = 0; n < 4; n++)
        *(char4*)(A + (size_t)(planebase + n) * 4194304u + idx4) =
            make_char4(e4[n][0], e4[n][1], e4[n][2], e4[n][3]);
}

// ---- prep: quantize + transpose weights -> Wt[proj][n'=4096][k=1024] -------
__global__ void prep_w(const float* __restrict__ W0, const float* __restrict__ W1,
                       signed char* __restrict__ Wt) {
    __shared__ float tile[32][33];
    int proj = blockIdx.z;
    const float* W = proj ? W1 : W0;             // [1024][4096] row-major
    int n0 = blockIdx.x * 32, k0 = blockIdx.y * 32;
    int tx = threadIdx.x, ty = threadIdx.y;
#pragma unroll
    for (int i = 0; i < 4; i++)
        tile[ty + i * 8][tx] = W[(size_t)(k0 + ty + i * 8) * 4096 + n0 + tx];
    __syncthreads();
#pragma unroll
    for (int i = 0; i < 4; i++) {
        int nn = n0 + ty + i * 8;
        float w = tile[tx][ty + i * 8];
        float xs = fminf(fmaxf(w, -0.9921875f), 0.9921875f);
        float e = rintf(xs * 128.f);             // Wq*128 integer, exact
        int np_ = ((nn & 1023) << 2) | (nn >> 10);
        Wt[(size_t)proj * 4194304u + (size_t)np_ * 1024 + k0 + tx] =
            (signed char)(int)e;
    }
}

// ---- FUSED main kernel: 8-plane int8 GEMM + e-quant + gates chain ----------
// 256 threads, 4 waves of 64x64. 4 LDS buffers, 3-deep counted-vmcnt pipeline.
// Barrier wait = s_waitcnt vmcnt(8) LGKMCNT(0): lgkmcnt(0) forces each wave's
// ds_reads of the buffer being retired to EXECUTE before it enters s_barrier
// (HW-enforced; immune to the compiler sinking MFMAs past the asm — rule #18,
// the round-9 race). vmcnt stays at 8 -> 2 future tiles' loads in flight.
#define GLOAD16(gp, lp) __builtin_amdgcn_global_load_lds( \
    (const __attribute__((address_space(1))) void*)(gp),  \
    (__attribute__((address_space(3))) void*)(lp), 16, 0, 0)

#define WB8 asm volatile("s_waitcnt vmcnt(8) lgkmcnt(0)" ::: "memory")
#define WB4 asm volatile("s_waitcnt vmcnt(4) lgkmcnt(0)" ::: "memory")
#define WB0 asm volatile("s_waitcnt vmcnt(0) lgkmcnt(0)" ::: "memory")
#define RAWBAR() do { __builtin_amdgcn_s_barrier(); \
                      asm volatile("" ::: "memory"); } while (0)

__global__ __launch_bounds__(256, 2) void gemm_fused(
    const signed char* __restrict__ A, const signed char* __restrict__ Wt,
    const float* __restrict__ Bf, const float* __restrict__ cx,
    float* __restrict__ out,
    const float* __restrict__ Ts, const float* __restrict__ Tt,
    const float* __restrict__ a1p, const float* __restrict__ a3p,
    const float* __restrict__ a4p, const float* __restrict__ a5p,
    const float* __restrict__ a6p, const float* __restrict__ a7p,
    const float* __restrict__ a8p, const float* __restrict__ a9p,
    const float* __restrict__ a10p, const float* __restrict__ a11p) {
    // 4 bufs x 16KB (A 8KB | B 8KB each) @0,16384,32768,49152;
    // epilogue gate tile 128 x 528B reuses the same space.
    __shared__ __align__(16) signed char lds[67584];
    int tid = threadIdx.x;
    int c0 = blockIdx.x * 128;                   // n' tile
    int b0 = blockIdx.y * 128;                   // batch tile

    // staging: row = tid>>2 (0..63), 16B chunk pre-swizzled (round-7 verified)
    int srow = tid >> 2;
    int g16  = (((tid & 3) + 4 - ((tid >> 3) & 3)) & 3) * 16;
    const signed char* Ab = A + (size_t)(b0 + srow) * 1024 + g16;
    const signed char* Bb = Wt + (size_t)(c0 + srow) * 1024 + g16;

    int w = tid >> 6, l = tid & 63;
    int wm = (w >> 1) * 64, wn = (w & 1) * 64;   // wave quadrant, 64x64
    int quad = l >> 4, lrow = l & 15;

    int stoff = tid * 16;
    int slot  = ((quad + (lrow >> 1)) & 3) * 16; // swizzled read slot
    int fAoff = (wm + lrow) * 64 + slot;         // + mt*1024
    int fBoff = 8192 + (wn + lrow) * 64 + slot;  // + nt*1024

    float biasA[4], biasB[4];
#pragma unroll
    for (int nt = 0; nt < 4; nt++) {
        int col = c0 + wn + nt * 16 + lrow;
        biasA[nt] = Bf[col];
        biasB[nt] = Bf[4096 + col];
    }

    i32x4 acc[4][4] = {};
    i32x4 packed[4][4];
#pragma unroll
    for (int mt = 0; mt < 4; mt++)
#pragma unroll
        for (int nt = 0; nt < 4; nt++)
            packed[mt][nt] = (i32x4){0x08000800, 0x08000800, 0x08000800, 0x08000800};

#define STAGE(bufbase, ts)                                              \
    do {                                                                \
        size_t ao = ((size_t)((ts) >> 4) << 22) + (size_t)(((ts) & 15) << 6); \
        size_t bo = (((ts) >= 64) ? (size_t)4194304u : 0) + (size_t)(((ts) & 15) << 6); \
        signed char* lb = lds + (bufbase) + stoff;                      \
        GLOAD16(Ab + ao,             lb);                               \
        GLOAD16(Ab + ao + 64 * 1024, lb + 4096);                        \
        GLOAD16(Bb + bo,             lb + 8192);                        \
        GLOAD16(Bb + bo + 64 * 1024, lb + 12288);                       \
    } while (0)

#define COMPUTE(bufbase)                                                \
    do {                                                                \
        const signed char* fA = lds + (bufbase) + fAoff;                \
        const signed char* fB = lds + (bufbase) + fBoff;                \
        i32x4 af[4], bfr[4];                                            \
        _Pragma("unroll")                                               \
        for (int mt = 0; mt < 4; mt++) af[mt] = *(const i32x4*)(fA + mt * 1024); \
        _Pragma("unroll")                                               \
        for (int nt = 0; nt < 4; nt++) bfr[nt] = *(const i32x4*)(fB + nt * 1024); \
        _Pragma("unroll")                                               \
        for (int mt = 0; mt < 4; mt++)                                  \
            _Pragma("unroll")                                           \
            for (int nt = 0; nt < 4; nt++)                              \
                acc[mt][nt] = __builtin_amdgcn_mfma_i32_16x16x64_i8(    \
                    af[mt], bfr[nt], acc[mt][nt], 0, 0, 0);             \
    } while (0)

#define FOLD(plane)                                                     \
    do {                                                                \
        int pl = (plane);                                               \
        int wgt = 8 >> (pl & 3);                                        \
        int mulw = (pl < 4) ? wgt : (wgt << 16);                        \
        _Pragma("unroll")                                               \
        for (int mt = 0; mt < 4; mt++)                                  \
            _Pragma("unroll")                                           \
            for (int nt = 0; nt < 4; nt++) {                            \
                float bb = (pl < 4) ? biasA[nt] : biasB[nt];            \
                _Pragma("unroll")                                       \
                for (int r = 0; r < 4; r++) {                           \
                    float t = (float)acc[mt][nt][r] * 0.0078125f + bb;  \
                    float tc = fminf(fmaxf(t, -127.f), 127.f);          \
                    packed[mt][nt][r] += mulw * (int)rintf(tc);         \
                    acc[mt][nt][r] = 0;                                 \
                }                                                       \
            }                                                           \
    } while (0)

    // prologue: stage tiles 0,1,2 (12 loads in flight); no drain.
    STAGE(0, 0);
    STAGE(16384, 1);
    STAGE(32768, 2);

    // main loop: t = 0..123, unrolled x4 (buffer bases compile-time const).
    for (int tb = 0; tb < 124; tb += 4) {
        WB8; RAWBAR(); STAGE(49152, tb + 3); COMPUTE(0);       // t = tb
        WB8; RAWBAR(); STAGE(0,     tb + 4); COMPUTE(16384);   // t = tb+1
        WB8; RAWBAR(); STAGE(16384, tb + 5); COMPUTE(32768);   // t = tb+2
        WB8; RAWBAR(); STAGE(32768, tb + 6); COMPUTE(49152);   // t = tb+3
        if ((tb & 15) == 12) FOLD((tb + 3) >> 4);              // t&15==15
    }
    // tail: t = 124..127 (stage only tile 127; drain 8 -> 4 -> 0)
    WB8; RAWBAR(); STAGE(49152, 127); COMPUTE(0);              // t = 124
    WB8; RAWBAR(); COMPUTE(16384);                             // t = 125
    WB4; RAWBAR(); COMPUTE(32768);                             // t = 126
    WB0; RAWBAR(); COMPUTE(49152);                             // t = 127
    FOLD(7);
#undef STAGE
#undef COMPUTE
#undef FOLD

    // ---- epilogue: gates -> LDS (528B stride), LSTM chain, store -----------
    __syncthreads();                             // all reads of bufs done
    float a1v = a1p[0], a11v = a11p[0];
#pragma unroll
    for (int mt = 0; mt < 4; mt++)
#pragma unroll
        for (int nt = 0; nt < 4; nt++)
#pragma unroll
            for (int r = 0; r < 4; r++) {
                int row = wm + mt * 16 + quad * 4 + r;
                int col = wn + nt * 16 + lrow;
                int pk = packed[mt][nt][r];
                int s1 = (pk & 0xFFFF) - 2048;
                int s2 = (pk >> 16) - 2048;
                float gate = ((float)s1 * 0.0009765625f) * a1v +
                             ((float)s2 * 0.0009765625f) * a11v;
                *(float*)(lds + row * 528 + col * 4) = gate;
            }
    __syncthreads();

    float a3 = a3p[0], a4 = a4p[0], a5 = a5p[0], a6 = a6p[0], a7 = a7p[0];
    float a8 = a8p[0], a9 = a9p[0], a10 = a10p[0], a11 = a11p[0];

    int row = tid >> 1;                          // 128 rows, 2 threads/row
    int hc  = (tid & 1) * 16;                    // local h base (0..31)
    size_t obase = (size_t)(b0 + row) * 1024 + (c0 >> 2) + hc;
    float cxa[16], nh[16], ncv[16];
#pragma unroll
    for (int q = 0; q < 4; q++) {
        float4 c4 = *(const float4*)(cx + obase + q * 4);
        cxa[q * 4] = c4.x; cxa[q * 4 + 1] = c4.y;
        cxa[q * 4 + 2] = c4.z; cxa[q * 4 + 3] = c4.w;
    }
#pragma unroll
    for (int j = 0; j < 16; j++) {
        float4 g4 = *(const float4*)(lds + row * 528 + (hc + j) * 16);
        float gi = g4.x, gj = g4.y, gf = g4.z, go = g4.w;
        float fg  = quantf(pactf(sig_lut(gf, Ts), a3), a3);
        float ig  = quantf(pactf(sig_lut(gi, Ts), a4), a4);
        float act = quantf(pactf(tanh_lut(gj, Tt), a5), a5);
        float og  = quantf(pactf(sig_lut(go, Ts), a6), a6);
        float gc  = quantf(pactf(cxa[j] * fg, a7), a7);
        float ai  = quantf(pactf(ig * act, a8), a8);
        float nc  = quantf(pactf(gc + ai, a9), a9);
        float ac  = quantf(pactf(tanh_lut(nc, Tt), a10), a10);
        float hh  = quantf(pactf(ac * og, a11), a11);
        nh[j]  = hh;
        ncv[j] = nc;
    }
#pragma unroll
    for (int q = 0; q < 4; q++) {
        *(float4*)(out + obase + q * 4) =
            (float4){nh[q * 4], nh[q * 4 + 1], nh[q * 4 + 2], nh[q * 4 + 3]};
        *(float4*)(out + 4194304u + obase + q * 4) =
            (float4){ncv[q * 4], ncv[q * 4 + 1], ncv[q * 4 + 2], ncv[q * 4 + 3]};
    }
}

// ---- launch ----------------------------------------------------------------
extern "C" void kernel_launch(void* const* d_in, const int* in_sizes, int n_in,
                              void* d_out, int out_size, void* d_ws, size_t ws_size,
                              hipStream_t stream) {
    const float* input = (const float*)d_in[0];
    const float* hx    = (const float*)d_in[1];
    const float* cx    = (const float*)d_in[2];
    const float* wih   = (const float*)d_in[3];
    const float* whh   = (const float*)d_in[4];
    const float* bih   = (const float*)d_in[5];
    const float* bhh   = (const float*)d_in[6];
    const float* a1  = (const float*)d_in[7];
    const float* a3  = (const float*)d_in[8];
    const float* a4  = (const float*)d_in[9];
    const float* a5  = (const float*)d_in[10];
    const float* a6  = (const float*)d_in[11];
    const float* a7  = (const float*)d_in[12];
    const float* a8  = (const float*)d_in[13];
    const float* a9  = (const float*)d_in[14];
    const float* a10 = (const float*)d_in[15];
    const float* a11 = (const float*)d_in[16];

    char* ws = (char*)d_ws;
    signed char* A  = (signed char*)ws;                     // 32 MB
    signed char* Wt = (signed char*)(ws + 33554432);        // 8 MB
    float*       Bf = (float*)(ws + 41943040);              // 32 KB
    float*       Ts = (float*)(ws + 41975808);              // 35492 B
    float*       Tt = (float*)(ws + 42011300);              // 18476 B

    prep_misc<<<35, 256, 0, stream>>>(bih, bhh, Bf, Ts, Tt);
    prep_act2<<<8192, 256, 0, stream>>>(input, hx, a1, a11, A);
    prep_w<<<dim3(128, 32, 2), dim3(32, 8), 0, stream>>>(wih, whh, Wt);
    gemm_fused<<<dim3(32, 32), 256, 0, stream>>>(A, Wt, Bf, cx, (float*)d_out,
                                                 Ts, Tt, a1, a3, a4, a5, a6,
                                                 a7, a8, a9, a10, a11);
}